// Round 1
// baseline (1000.260 us; speedup 1.0000x reference)
//
#include <hip/hip_runtime.h>

// Problem constants (from reference):
//   x: (2, 64, 32*64*64=131072) fp32, LN over 64 channels,
//   w_qkv: (384, 64)  rows 0..127=q, 128..255=k, 256..383=v  (h*32+d within each)
//   q: softmax over d (local, 32), * 32^-0.5
//   k: softmax over n (global)  -> ctx[h,d,e] = sum_n softmax_k[d,n] * v[e,n]
//   out[e,n] = sum_d ctx[d,e] q[d,n];  y = w_out(64x128) @ out + b_out; LN2.
#define NCOL 131072
#define CH 64
#define CHUNKS_PER_B 512   // 512 chunks of 256 columns each
#define NBLK_A 1024        // 2 batches * 512 chunks

__device__ __forceinline__ float dot64(const float* __restrict__ w, const float (&xv)[64]) {
  // 4 independent FMA chains to hide v_fma latency
  float a0=0.f,a1=0.f,a2=0.f,a3=0.f;
  #pragma unroll
  for (int c=0;c<64;c+=4){
    a0 = fmaf(w[c+0], xv[c+0], a0);
    a1 = fmaf(w[c+1], xv[c+1], a1);
    a2 = fmaf(w[c+2], xv[c+2], a2);
    a3 = fmaf(w[c+3], xv[c+3], a3);
  }
  return (a0+a1)+(a2+a3);
}

// Kernel A: LN1 + k/v matvec + exp(k) + partial ctx/Z per 256-column block.
__global__ __launch_bounds__(256) void kA(
    const float* __restrict__ x, const float* __restrict__ g1, const float* __restrict__ b1,
    const float* __restrict__ wqkv, float* __restrict__ pctx, float* __restrict__ pz)
{
  __shared__ float ek_lds[32*257];   // [d][col], stride 257: conflict-free
  __shared__ float v_lds[256*36];    // [col][e], stride 36: 16B-aligned float4 reads
  const int t = threadIdx.x;
  const int bid = blockIdx.x;
  const int b = bid >> 9;
  const int chunk = bid & 511;
  const long col = (long)chunk*256 + t;
  const float* xp = x + (long)b*CH*NCOL + col;

  // LN1: load column into registers (coalesced per channel)
  float xv[64];
  float s=0.f, ss=0.f;
  #pragma unroll
  for (int c=0;c<64;c++){ float u = xp[(long)c*NCOL]; xv[c]=u; s+=u; ss=fmaf(u,u,ss); }
  const float mean = s*(1.f/64.f);
  const float rstd = rsqrtf(ss*(1.f/64.f) - mean*mean + 1e-5f);
  #pragma unroll
  for (int c=0;c<64;c++){ xv[c] = (xv[c]-mean)*rstd*g1[c] + b1[c]; }

  const int d  = t >> 3;         // ctx-owner row
  const int e0 = (t & 7) << 2;   // ctx-owner e-quad

  for (int h=0; h<4; h++){
    const float* wk = wqkv + (128 + h*32)*64;
    const float* wv = wqkv + (256 + h*32)*64;
    #pragma unroll 2
    for (int dd=0; dd<32; dd++){
      ek_lds[dd*257 + t] = __expf(dot64(wk + dd*64, xv));  // no max-sub: |k|<~6, safe
    }
    #pragma unroll 2
    for (int ee=0; ee<32; ee++){
      v_lds[t*36 + ee] = dot64(wv + ee*64, xv);
    }
    __syncthreads();
    // each thread owns (d, e0..e0+3): accumulate over the 256 columns
    float a0=0.f,a1=0.f,a2=0.f,a3=0.f,zacc=0.f;
    const float* ekrow = ek_lds + d*257;
    #pragma unroll 4
    for (int cc=0; cc<256; cc++){
      const float ekv = ekrow[cc];
      const float4 vv = *(const float4*)(v_lds + cc*36 + e0);
      a0 = fmaf(ekv, vv.x, a0);
      a1 = fmaf(ekv, vv.y, a1);
      a2 = fmaf(ekv, vv.z, a2);
      a3 = fmaf(ekv, vv.w, a3);
      zacc += ekv;
    }
    *(float4*)(pctx + (((long)bid*4 + h)*32 + d)*32 + e0) = make_float4(a0,a1,a2,a3);
    if ((t & 7) == 0) pz[((long)bid*4 + h)*32 + d] = zacc;
    __syncthreads();
  }
}

// Kernel R: reduce 512 partials per batch, divide by Z -> ctx_final (2*4096 floats)
__global__ __launch_bounds__(256) void kR(
    const float* __restrict__ pctx, const float* __restrict__ pz, float* __restrict__ ctxf)
{
  const int idx = blockIdx.x*256 + threadIdx.x; // 0..8191
  const int b = idx >> 12;
  const int r = idx & 4095;       // (h*32+d)*32+e
  const int hd = r >> 5;
  float sum=0.f, z=0.f;
  for (int ch=0; ch<CHUNKS_PER_B; ch++){
    const long blk = (long)b*CHUNKS_PER_B + ch;
    sum += pctx[blk*4096 + r];
    z   += pz[blk*128 + hd];
  }
  ctxf[idx] = sum / z;
}

// Kernel B: LN1 (recomputed) + q matvec + softmax*scale + ctx^T q + w_out + LN2
__global__ __launch_bounds__(256) void kB(
    const float* __restrict__ x, const float* __restrict__ g1, const float* __restrict__ b1,
    const float* __restrict__ wqkv, const float* __restrict__ ctxf,
    const float* __restrict__ wout, const float* __restrict__ bout,
    const float* __restrict__ g2, const float* __restrict__ b2,
    float* __restrict__ y)
{
  __shared__ float ctx_s[4096];
  const int t = threadIdx.x;
  const int bid = blockIdx.x;
  const int b = bid >> 9;
  const int chunk = bid & 511;
  const long col = (long)chunk*256 + t;

  #pragma unroll
  for (int i=0;i<16;i++) ctx_s[i*256+t] = ctxf[(long)b*4096 + i*256 + t];
  __syncthreads();

  const float* xp = x + (long)b*CH*NCOL + col;
  float xv[64];
  float s=0.f, ss=0.f;
  #pragma unroll
  for (int c=0;c<64;c++){ float u = xp[(long)c*NCOL]; xv[c]=u; s+=u; ss=fmaf(u,u,ss); }
  const float mean = s*(1.f/64.f);
  const float rstd = rsqrtf(ss*(1.f/64.f) - mean*mean + 1e-5f);
  #pragma unroll
  for (int c=0;c<64;c++){ xv[c] = (xv[c]-mean)*rstd*g1[c] + b1[c]; }

  float yacc[64];
  #pragma unroll
  for (int o=0;o<64;o++) yacc[o]=0.f;

  const float4* ctx4 = (const float4*)ctx_s;

  for (int h=0; h<4; h++){
    const float* wq = wqkv + (h*32)*64;
    float qe[32];
    float qsum = 0.f;
    #pragma unroll
    for (int dd=0; dd<32; dd++){
      const float e = __expf(dot64(wq + dd*64, xv));
      qe[dd] = e;
      qsum += e;
    }
    const float qscale = 0.17677669529663687f / qsum;  // 32^-0.5 / sum
    #pragma unroll
    for (int dd=0; dd<32; dd++) qe[dd] *= qscale;

    for (int e4=0; e4<8; e4++){
      float4 ov = make_float4(0.f,0.f,0.f,0.f);
      #pragma unroll
      for (int dd=0; dd<32; dd++){
        const float4 cv = ctx4[(h*32+dd)*8 + e4];   // broadcast ds_read_b128
        ov.x = fmaf(cv.x, qe[dd], ov.x);
        ov.y = fmaf(cv.y, qe[dd], ov.y);
        ov.z = fmaf(cv.z, qe[dd], ov.z);
        ov.w = fmaf(cv.w, qe[dd], ov.w);
      }
      const int ec = h*32 + e4*4;
      const float* wo = wout + ec;
      #pragma unroll
      for (int o=0;o<64;o++){
        yacc[o] = fmaf(wo[o*128+0], ov.x,
                  fmaf(wo[o*128+1], ov.y,
                  fmaf(wo[o*128+2], ov.z,
                  fmaf(wo[o*128+3], ov.w, yacc[o]))));
      }
    }
  }

  // + b_out, LN2, store
  float s2=0.f, ss2=0.f;
  #pragma unroll
  for (int o=0;o<64;o++){ float u = yacc[o] + bout[o]; yacc[o]=u; s2+=u; ss2=fmaf(u,u,ss2); }
  const float mean2 = s2*(1.f/64.f);
  const float rstd2 = rsqrtf(ss2*(1.f/64.f) - mean2*mean2 + 1e-5f);
  float* yp = y + (long)b*CH*NCOL + col;
  #pragma unroll
  for (int o=0;o<64;o++) yp[(long)o*NCOL] = (yacc[o]-mean2)*rstd2*g2[o] + b2[o];
}

extern "C" void kernel_launch(void* const* d_in, const int* in_sizes, int n_in,
                              void* d_out, int out_size, void* d_ws, size_t ws_size,
                              hipStream_t stream)
{
  const float* x    = (const float*)d_in[0];
  const float* g1   = (const float*)d_in[1];
  const float* b1   = (const float*)d_in[2];
  const float* wqkv = (const float*)d_in[3];
  const float* wout = (const float*)d_in[4];
  const float* bout = (const float*)d_in[5];
  const float* g2   = (const float*)d_in[6];
  const float* b2   = (const float*)d_in[7];
  float* y  = (float*)d_out;
  float* ws = (float*)d_ws;

  float* pctx = ws;                                   // 1024*4096 floats (16 MiB)
  float* pz   = ws + (long)NBLK_A*4096;               // 1024*128 floats
  float* ctxf = ws + (long)NBLK_A*4096 + (long)NBLK_A*128;  // 8192 floats

  hipLaunchKernelGGL(kA, dim3(NBLK_A), dim3(256), 0, stream, x, g1, b1, wqkv, pctx, pz);
  hipLaunchKernelGGL(kR, dim3(32), dim3(256), 0, stream, pctx, pz, ctxf);
  hipLaunchKernelGGL(kB, dim3(NBLK_A), dim3(256), 0, stream,
                     x, g1, b1, wqkv, ctxf, wout, bout, g2, b2, y);
}

// Round 2
// 293.165 us; speedup vs baseline: 3.4119x; 3.4119x over previous
//
#include <hip/hip_runtime.h>

// LinearAttention fused, MFMA (bf16 in / fp32 acc) restructure.
//   kA: LN1 -> k,v GEMM -> exp(k) -> ctx partial = ek @ v^T  (per 256-col block)
//   kR: reduce ctx partials / Z
//   kM: M[b][h][o][dd] = sum_e wout[o, h*32+e] * ctx[b][h][dd][e]   (w_out pre-fused)
//   kB: LN1 -> q GEMM -> softmax(d)*scale -> y = M @ qs -> +b_out -> LN2
#define NCOL 131072
#define CH 64

typedef float floatx4 __attribute__((ext_vector_type(4)));
typedef __bf16 bf16x8 __attribute__((ext_vector_type(8)));
typedef unsigned int u32x4 __attribute__((ext_vector_type(4)));
typedef unsigned int u32x2 __attribute__((ext_vector_type(2)));

union FragU { u32x4 q; bf16x8 v; unsigned short us[8]; };

__device__ __forceinline__ unsigned short f2bf(float f){
  union { float f; unsigned u; } x{f};
  unsigned r = x.u + 0x7fffu + ((x.u >> 16) & 1u);
  return (unsigned short)(r >> 16);
}
__device__ __forceinline__ float bf2f(unsigned short h){
  union { unsigned u; float f; } x{(unsigned)h << 16};
  return x.f;
}

// LN over 64 channels for column (thread t), write bf16 column to xn_s[t][0..63], stride 72.
__device__ __forceinline__ void ln_stage(const float* __restrict__ xp,
    const float* __restrict__ g, const float* __restrict__ bb,
    unsigned short* __restrict__ xn_s, int t)
{
  float xv[64]; float s = 0.f, ss = 0.f;
  #pragma unroll
  for (int c = 0; c < 64; c++){ float u = xp[(long)c*NCOL]; xv[c] = u; s += u; ss = fmaf(u,u,ss); }
  const float mean = s * (1.f/64.f);
  const float rstd = rsqrtf(ss * (1.f/64.f) - mean*mean + 1e-5f);
  #pragma unroll
  for (int c = 0; c < 64; c++) xv[c] = (xv[c]-mean)*rstd*g[c] + bb[c];
  #pragma unroll
  for (int j = 0; j < 8; j++){
    FragU u;
    #pragma unroll
    for (int e = 0; e < 8; e++) u.us[e] = f2bf(xv[j*8+e]);
    *(u32x4*)(xn_s + t*72 + j*8) = u.q;
  }
}

// ---------------- kA ----------------
__global__ __launch_bounds__(256) void kA(
    const float* __restrict__ x, const float* __restrict__ g1, const float* __restrict__ b1,
    const float* __restrict__ wqkv, float* __restrict__ pctx, float* __restrict__ pz)
{
  __shared__ __align__(16) char smem[74752];
  unsigned short* xn_s = (unsigned short*)smem;             // 256*72*2 = 36864 B
  unsigned short* ek_s = (unsigned short*)(smem + 36864);   // 32*264*2 = 16896 B
  unsigned short* v_s  = (unsigned short*)(smem + 53760);   // 16896 B
  float* Zp            = (float*)(smem + 70656);            // 4*256*4  = 4096 B

  const int t = threadIdx.x;
  const int bid = blockIdx.x;
  const int b = bid >> 9;
  const long col0 = (long)(bid & 511) * 256;
  const int w = t >> 6, lane = t & 63, qq = lane >> 4, l16 = lane & 15;

  ln_stage(x + (long)b*CH*NCOL + col0 + t, g1, b1, xn_s, t);
  __syncthreads();

  // B fragments of xn for this wave's 4 col-tiles (wave-private cols [64w,64w+64))
  FragU bx[4][2];
  #pragma unroll
  for (int nt = 0; nt < 4; nt++)
    #pragma unroll
    for (int ks = 0; ks < 2; ks++)
      bx[nt][ks].q = *(const u32x4*)(xn_s + ((4*w+nt)*16 + l16)*72 + ks*32 + qq*8);

  floatx4 cc[4][2][2];
  #pragma unroll
  for (int h = 0; h < 4; h++)
    #pragma unroll
    for (int dt = 0; dt < 2; dt++)
      #pragma unroll
      for (int et = 0; et < 2; et++)
        cc[h][dt][et] = floatx4{0.f,0.f,0.f,0.f};

  #pragma unroll
  for (int h = 0; h < 4; h++){
    // k (rt 0,1) and v (rt 2,3) GEMM, 16 rows per rt
    #pragma unroll
    for (int rt = 0; rt < 4; rt++){
      const int row0 = ((rt < 2) ? 128 : 256) + h*32 + (rt & 1)*16;
      const float* wr = wqkv + (row0 + l16)*64 + qq*8;
      FragU a0, a1;
      #pragma unroll
      for (int j = 0; j < 8; j++){ a0.us[j] = f2bf(wr[j]); a1.us[j] = f2bf(wr[32+j]); }
      unsigned short* dst = ((rt < 2) ? ek_s : v_s) + ((rt & 1)*16 + qq*4)*264;
      #pragma unroll
      for (int nt = 0; nt < 4; nt++){
        floatx4 c = floatx4{0.f,0.f,0.f,0.f};
        c = __builtin_amdgcn_mfma_f32_16x16x32_bf16(a0.v, bx[nt][0].v, c, 0, 0, 0);
        c = __builtin_amdgcn_mfma_f32_16x16x32_bf16(a1.v, bx[nt][1].v, c, 0, 0, 0);
        const int colb = (4*w+nt)*16 + l16;
        if (rt < 2){
          #pragma unroll
          for (int r = 0; r < 4; r++) dst[r*264 + colb] = f2bf(__expf(c[r]));
        } else {
          #pragma unroll
          for (int r = 0; r < 4; r++) dst[r*264 + colb] = f2bf(c[r]);
        }
      }
    }
    __syncthreads();
    // Z partials: thread sums 32 cols of row d
    {
      const int d = t & 31, part = t >> 5;
      const unsigned short* p = ek_s + d*264 + part*32;
      float zs = 0.f;
      #pragma unroll
      for (int j = 0; j < 4; j++){
        FragU u; u.q = *(const u32x4*)(p + j*8);
        #pragma unroll
        for (int e = 0; e < 8; e++) zs += bf2f(u.us[e]);
      }
      Zp[h*256 + part*32 + d] = zs;
    }
    // ctx MFMAs: D[d][e] += sum_col ek[d,col] v[e,col]; wave w covers cols [64w,64w+64)
    #pragma unroll
    for (int kk = 0; kk < 2; kk++){
      const int ks2 = 2*w + kk;
      FragU ae[2], bv[2];
      #pragma unroll
      for (int dt = 0; dt < 2; dt++) ae[dt].q = *(const u32x4*)(ek_s + (dt*16 + l16)*264 + ks2*32 + qq*8);
      #pragma unroll
      for (int et = 0; et < 2; et++) bv[et].q = *(const u32x4*)(v_s + (et*16 + l16)*264 + ks2*32 + qq*8);
      #pragma unroll
      for (int dt = 0; dt < 2; dt++)
        #pragma unroll
        for (int et = 0; et < 2; et++)
          cc[h][dt][et] = __builtin_amdgcn_mfma_f32_16x16x32_bf16(ae[dt].v, bv[et].v, cc[h][dt][et], 0, 0, 0);
    }
    __syncthreads();
  }

  // cross-wave ctx reduction via smem (alias over xn/ek/v regions, 64 KiB)
  float* scr = (float*)smem;
  #pragma unroll
  for (int h = 0; h < 4; h++)
    #pragma unroll
    for (int dt = 0; dt < 2; dt++)
      #pragma unroll
      for (int et = 0; et < 2; et++)
        ((floatx4*)scr)[(w*16 + h*4 + dt*2 + et)*64 + lane] = cc[h][dt][et];
  __syncthreads();
  #pragma unroll
  for (int j = 0; j < 16; j++){
    const int idx = j*256 + t;
    pctx[(long)bid*4096 + idx] = scr[idx] + scr[4096+idx] + scr[8192+idx] + scr[12288+idx];
  }
  if (t < 128){
    const int h = t >> 5, d = t & 31;
    float z = 0.f;
    #pragma unroll
    for (int part = 0; part < 8; part++) z += Zp[h*256 + part*32 + d];
    pz[((long)bid*4 + h)*32 + d] = z;
  }
}

// ---------------- kR: reduce partials, divide by Z ----------------
__global__ __launch_bounds__(256) void kR(
    const float* __restrict__ pctx, const float* __restrict__ pz, float* __restrict__ ctxf)
{
  const int idx = blockIdx.x*256 + threadIdx.x;  // 0..8191
  const int b = idx >> 12, r = idx & 4095;
  const int h = r >> 10, tile = (r >> 8) & 3, lane = (r >> 2) & 63, rg = r & 3;
  const int dt = tile >> 1, et = tile & 1, qq = lane >> 4, l16 = lane & 15;
  const int d = dt*16 + qq*4 + rg, e = et*16 + l16;
  float s = 0.f, z = 0.f;
  #pragma unroll 4
  for (int blk = b*512; blk < (b+1)*512; blk++){
    s += pctx[(long)blk*4096 + r];
    z += pz[(long)blk*128 + h*32 + d];
  }
  ctxf[((b*4 + h)*32 + d)*32 + e] = s / z;
}

// ---------------- kM: fuse w_out into ctx ----------------
__global__ __launch_bounds__(256) void kM(
    const float* __restrict__ ctxf, const float* __restrict__ wout, float* __restrict__ Mg)
{
  const int idx = blockIdx.x*256 + threadIdx.x;  // 0..16383
  const int b = idx >> 13, rem = idx & 8191;
  const int h = rem >> 11, o = (rem >> 5) & 63, dd = rem & 31;
  float m = 0.f;
  #pragma unroll
  for (int ee = 0; ee < 32; ee++)
    m = fmaf(wout[o*128 + h*32 + ee], ctxf[((b*4 + h)*32 + dd)*32 + ee], m);
  Mg[((b*4 + h)*64 + o)*32 + dd] = m;
}

// ---------------- kB ----------------
__global__ __launch_bounds__(256) void kB(
    const float* __restrict__ x, const float* __restrict__ g1, const float* __restrict__ b1,
    const float* __restrict__ wqkv, const float* __restrict__ Mg,
    const float* __restrict__ bout, const float* __restrict__ g2, const float* __restrict__ b2,
    float* __restrict__ y)
{
  __shared__ __align__(16) char smem[58112];
  unsigned short* xn_s = (unsigned short*)smem;             // 36864 B
  unsigned short* qs_s = (unsigned short*)(smem + 36864);   // 256*40*2 = 20480 B
  float* sp            = (float*)(smem + 57344);            // 192 floats

  const int t = threadIdx.x;
  const int bid = blockIdx.x;
  const int b = bid >> 9;
  const long col0 = (long)(bid & 511) * 256;
  const int w = t >> 6, lane = t & 63, qq = lane >> 4, l16 = lane & 15;

  if (t < 64){ sp[t] = bout[t]; sp[64+t] = g2[t]; sp[128+t] = b2[t]; }
  ln_stage(x + (long)b*CH*NCOL + col0 + t, g1, b1, xn_s, t);
  __syncthreads();

  FragU bx[4][2];
  #pragma unroll
  for (int nt = 0; nt < 4; nt++)
    #pragma unroll
    for (int ks = 0; ks < 2; ks++)
      bx[nt][ks].q = *(const u32x4*)(xn_s + ((4*w+nt)*16 + l16)*72 + ks*32 + qq*8);

  floatx4 yacc[4][4];
  #pragma unroll
  for (int ot = 0; ot < 4; ot++)
    #pragma unroll
    for (int nt = 0; nt < 4; nt++)
      yacc[ot][nt] = floatx4{0.f,0.f,0.f,0.f};

  #pragma unroll
  for (int h = 0; h < 4; h++){
    // q GEMM -> exp -> qs_s[col][dd] (stride 40), packed b64 writes
    #pragma unroll
    for (int ot = 0; ot < 2; ot++){
      const int row0 = h*32 + ot*16;
      const float* wr = wqkv + (row0 + l16)*64 + qq*8;
      FragU a0, a1;
      #pragma unroll
      for (int j = 0; j < 8; j++){ a0.us[j] = f2bf(wr[j]); a1.us[j] = f2bf(wr[32+j]); }
      #pragma unroll
      for (int nt = 0; nt < 4; nt++){
        floatx4 c = floatx4{0.f,0.f,0.f,0.f};
        c = __builtin_amdgcn_mfma_f32_16x16x32_bf16(a0.v, bx[nt][0].v, c, 0, 0, 0);
        c = __builtin_amdgcn_mfma_f32_16x16x32_bf16(a1.v, bx[nt][1].v, c, 0, 0, 0);
        const int colb = (4*w+nt)*16 + l16;
        const unsigned short p0 = f2bf(__expf(c[0])), p1 = f2bf(__expf(c[1]));
        const unsigned short p2 = f2bf(__expf(c[2])), p3 = f2bf(__expf(c[3]));
        u32x2 pk; pk[0] = (unsigned)p0 | ((unsigned)p1 << 16); pk[1] = (unsigned)p2 | ((unsigned)p3 << 16);
        *(u32x2*)(qs_s + colb*40 + ot*16 + qq*4) = pk;
      }
    }
    __syncthreads();
    // per-column softmax normalize * scale (thread t owns col t)
    {
      unsigned short* p = qs_s + t*40;
      FragU u[4]; float s = 0.f;
      #pragma unroll
      for (int j = 0; j < 4; j++){
        u[j].q = *(const u32x4*)(p + j*8);
        #pragma unroll
        for (int e = 0; e < 8; e++) s += bf2f(u[j].us[e]);
      }
      const float sc = 0.17677669529663687f / s;   // 32^-0.5 / sum
      #pragma unroll
      for (int j = 0; j < 4; j++){
        #pragma unroll
        for (int e = 0; e < 8; e++) u[j].us[e] = f2bf(bf2f(u[j].us[e]) * sc);
        *(u32x4*)(p + j*8) = u[j].q;
      }
    }
    __syncthreads();
    // y += M_h @ qs_h
    #pragma unroll
    for (int ot = 0; ot < 4; ot++){
      const float* mp = Mg + (((long)b*4 + h)*64 + ot*16 + l16)*32 + qq*8;
      FragU am;
      #pragma unroll
      for (int j = 0; j < 8; j++) am.us[j] = f2bf(mp[j]);
      #pragma unroll
      for (int nt = 0; nt < 4; nt++){
        FragU bq; bq.q = *(const u32x4*)(qs_s + ((4*w+nt)*16 + l16)*40 + qq*8);
        yacc[ot][nt] = __builtin_amdgcn_mfma_f32_16x16x32_bf16(am.v, bq.v, yacc[ot][nt], 0, 0, 0);
      }
    }
    __syncthreads();
  }

  // epilogue: +b_out, LN2 over 64 rows (rows live on lanes {l16, l16+16, l16+32, l16+48})
  const long ybase = (long)b*CH*NCOL;
  #pragma unroll
  for (int nt = 0; nt < 4; nt++){
    const long colg = col0 + (4*w+nt)*16 + l16;
    float vals[16]; float s = 0.f, ss = 0.f;
    #pragma unroll
    for (int ot = 0; ot < 4; ot++)
      #pragma unroll
      for (int r = 0; r < 4; r++){
        const float v = yacc[ot][nt][r] + sp[ot*16 + qq*4 + r];
        vals[ot*4+r] = v; s += v; ss = fmaf(v, v, ss);
      }
    s  += __shfl_xor(s, 16, 64);  s  += __shfl_xor(s, 32, 64);
    ss += __shfl_xor(ss, 16, 64); ss += __shfl_xor(ss, 32, 64);
    const float mean = s * (1.f/64.f);
    const float rstd = rsqrtf(ss * (1.f/64.f) - mean*mean + 1e-5f);
    #pragma unroll
    for (int ot = 0; ot < 4; ot++)
      #pragma unroll
      for (int r = 0; r < 4; r++){
        const int row = ot*16 + qq*4 + r;
        y[ybase + (long)row*NCOL + colg] = (vals[ot*4+r]-mean)*rstd*sp[64+row] + sp[128+row];
      }
  }
}

extern "C" void kernel_launch(void* const* d_in, const int* in_sizes, int n_in,
                              void* d_out, int out_size, void* d_ws, size_t ws_size,
                              hipStream_t stream)
{
  const float* x    = (const float*)d_in[0];
  const float* g1   = (const float*)d_in[1];
  const float* b1   = (const float*)d_in[2];
  const float* wqkv = (const float*)d_in[3];
  const float* wout = (const float*)d_in[4];
  const float* bout = (const float*)d_in[5];
  const float* g2   = (const float*)d_in[6];
  const float* b2   = (const float*)d_in[7];
  float* y  = (float*)d_out;
  float* ws = (float*)d_ws;

  float* pctx = ws;                         // 1024*4096 = 4,194,304 floats
  float* pz   = ws + 4194304;               // 1024*128  =   131,072
  float* ctxf = pz + 131072;                //               8,192
  float* Mg   = ctxf + 8192;                //              16,384

  hipLaunchKernelGGL(kA, dim3(1024), dim3(256), 0, stream, x, g1, b1, wqkv, pctx, pz);
  hipLaunchKernelGGL(kR, dim3(32),   dim3(256), 0, stream, pctx, pz, ctxf);
  hipLaunchKernelGGL(kM, dim3(64),   dim3(256), 0, stream, ctxf, wout, Mg);
  hipLaunchKernelGGL(kB, dim3(1024), dim3(256), 0, stream, x, g1, b1, wqkv, Mg, bout, g2, g2 ? b2 : b2, y);
}